// Round 8
// baseline (85.863 us; speedup 1.0000x reference)
//
#include <hip/hip_runtime.h>
#include <math.h>

typedef _Float16 half_t;
typedef _Float16 h2 __attribute__((ext_vector_type(2)));
typedef unsigned int uint;
typedef unsigned long long u64;

#define TPB 256

// pack two floats into a half2 bit pattern
__device__ __forceinline__ uint pack_h2f(float a, float b) {
  half_t ha = (half_t)a, hb = (half_t)b;
  unsigned short ua = __builtin_bit_cast(unsigned short, ha);
  unsigned short ub = __builtin_bit_cast(unsigned short, hb);
  return (uint)ua | ((uint)ub << 16);
}

__device__ __forceinline__ float silu_f(float x) {
  float e = __expf(-x);
  return x * __builtin_amdgcn_rcpf(1.0f + e);
}

// acc += silu*bw + sum_g basis[g]*w[g]   (fp16 dot2 pairs, fp32 accumulate)
// w points at 5 uniform dwords in GLOBAL memory (scalar-cache path, keeps
// weight traffic off the LDS pipe — K2 vs K3 A/B evidence).
__device__ __forceinline__ float dot8(uint d0, uint d1, uint d2, uint d3,
                                      float sv, const uint* __restrict__ w,
                                      float acc) {
  acc = fmaf(sv, __uint_as_float(w[4]), acc);
#if __has_builtin(__builtin_amdgcn_fdot2)
  acc = __builtin_amdgcn_fdot2(__builtin_bit_cast(h2, d0), __builtin_bit_cast(h2, w[0]), acc, false);
  acc = __builtin_amdgcn_fdot2(__builtin_bit_cast(h2, d1), __builtin_bit_cast(h2, w[1]), acc, false);
  acc = __builtin_amdgcn_fdot2(__builtin_bit_cast(h2, d2), __builtin_bit_cast(h2, w[2]), acc, false);
  acc = __builtin_amdgcn_fdot2(__builtin_bit_cast(h2, d3), __builtin_bit_cast(h2, w[3]), acc, false);
#else
  uint dd[4] = {d0, d1, d2, d3};
#pragma unroll
  for (int k = 0; k < 4; ++k) {
    h2 f = __builtin_bit_cast(h2, dd[k]);
    h2 wv = __builtin_bit_cast(h2, w[k]);
    acc = fmaf((float)f.x, (float)wv.x, acc);
    acc = fmaf((float)f.y, (float)wv.y, acc);
  }
#endif
  return acc;
}

// Uniform-knot cubic B-spline dense-8 fp16 fragment, built in registers via a
// 128-bit shift scatter (numerics validated K4/K5/K7, absmax 0.0156). No silu.
__device__ __forceinline__ uint4 make_basis(float x) {
  float s = fmaf(x, 2.5f, 5.5f);       // (x - (-2.2)) / 0.4
  float sf = floorf(s);
  float t = s - sf;
  int p = (int)sf - 3;                 // first nonzero basis index (may be <0)
  float omt = 1.0f - t, t2 = t * t;
  float B0 = (1.0f / 6.0f) * omt * omt * omt;
  float B3 = (1.0f / 6.0f) * t2 * t;
  float B1 = fmaf(0.5f * t, t2, 2.0f / 3.0f - t2);
  float B2 = 1.0f - B0 - B1 - B3;      // partition of unity
  u64 A = ((u64)pack_h2f(B2, B3) << 32) | pack_h2f(B0, B1);
  int n = p < 0 ? -p : 0;              // halves below 0: pre-drop
  A = (n >= 4) ? 0ull : (A >> (16 * n));
  int pc = p < 0 ? 0 : (p > 9 ? 9 : p);
  int sh = 16 * pc;                    // 0..144
  u64 lo = (sh < 64) ? (A << sh) : 0ull;
  u64 hi = (sh == 0) ? 0ull
         : (sh < 64) ? (A >> (64 - sh))
         : (sh < 128) ? (A << (sh - 64)) : 0ull;
  return make_uint4((uint)lo, (uint)(lo >> 32), (uint)hi, (uint)(hi >> 32));
}

// Precompute packed fp16 weights into d_ws (global; scalar-cache reads):
// W[t*5]        t=o*9+tap        (layer 1, 18 entries)
// W[90 + q*5]   q=(o*2+ci)*9+tap (layer 2, 36 entries)
__global__ void pack_w(const float* __restrict__ bw1, const float* __restrict__ sw1,
                       const float* __restrict__ sc1, const float* __restrict__ bw2,
                       const float* __restrict__ sw2, const float* __restrict__ sc2,
                       uint* __restrict__ W) {
  const int t = threadIdx.x;
  if (t < 18) {
    const float scv = sc1[t];
    uint* dst = W + t * 5;
#pragma unroll
    for (int j = 0; j < 4; ++j)
      dst[j] = pack_h2f(sw1[t * 8 + 2 * j] * scv, sw1[t * 8 + 2 * j + 1] * scv);
    dst[4] = __float_as_uint(bw1[t]);
  } else if (t < 54) {
    const int q = t - 18;
    const float scv = sc2[q];
    uint* dst = W + 90 + q * 5;
#pragma unroll
    for (int j = 0; j < 4; ++j)
      dst[j] = pack_h2f(sw2[q * 8 + 2 * j] * scv, sw2[q * 8 + 2 * j + 1] * scv);
    dst[4] = __float_as_uint(bw2[q]);
  }
}

// LDS dword map (22.2 KB):
//  F1  [0,3600):     900 x uint4 basis frags (30x30 padded), 16B slots
//  F2D [3600,5168):  392 x uint4 basis frags (2ch x 14x14)
//  F2S [5168,5560):  392 x f32 silu
//  P   alias [0,784): f32 partials for stage 4 (F1 dead by then)
#define F2DB 3600
#define F2SB 5168

__global__ __launch_bounds__(TPB, 5) void kan_fwd(
    const float* __restrict__ x, const uint* __restrict__ W,
    float* __restrict__ out)
{
  __shared__ __align__(16) uint lds[5560];
  float* P = (float*)lds;

  const int tid = threadIdx.x;
  const float* xb = x + (size_t)blockIdx.x * 784;

  // ---- Stage 1: basis frags of padded 30x30 input, one b128 per pixel ----
  for (int ii = tid; ii < 900; ii += TPB) {
    int r = ii / 30, c = ii % 30;
    bool inter = ((uint)(r - 1) < 28u) && ((uint)(c - 1) < 28u);
    int xi = (r - 1) * 28 + (c - 1);
    xi = min(max(xi, 0), 783);
    float xv = xb[xi];
    xv = inter ? xv : 0.0f;              // padding pixels get basis of 0
    uint4 bs = make_basis(xv);
    *(uint4*)&lds[ii * 4] = bs;
  }
  __syncthreads();

  // ---- Stage 2: L1 conv (2x2 pool quad per thread) + pool + F2 features ----
  if (tid < 196) {
    const int ph = tid / 14, pw = tid % 14;
    // silu inputs re-read from global (L1-hot; TA pipe, off the LDS pipe)
    float xv[16];
#pragma unroll
    for (int r = 0; r < 4; ++r) {
      int ir = 2 * ph + r - 1;
#pragma unroll
      for (int c = 0; c < 4; ++c) {
        int ic = 2 * pw + c - 1;
        bool ok = ((uint)ir < 28u) && ((uint)ic < 28u);
        int xi = min(max(ir * 28 + ic, 0), 783);
        float v = xb[xi];
        xv[r * 4 + c] = ok ? v : 0.0f;
      }
    }
    float acc[2][4];
#pragma unroll
    for (int o = 0; o < 2; ++o)
#pragma unroll
      for (int q = 0; q < 4; ++q) acc[o][q] = 0.0f;
#pragma unroll
    for (int r = 0; r < 4; ++r) {
#pragma unroll
      for (int c = 0; c < 4; ++c) {
        const uint4 fr = *(const uint4*)&lds[((2 * ph + r) * 30 + (2 * pw + c)) * 4];
        const float sv = silu_f(xv[r * 4 + c]);
#pragma unroll
        for (int dh = 0; dh < 2; ++dh) {
          if (r - dh < 0 || r - dh > 2) continue;
#pragma unroll
          for (int dw = 0; dw < 2; ++dw) {
            if (c - dw < 0 || c - dw > 2) continue;
            const int tap = (r - dh) * 3 + (c - dw);
#pragma unroll
            for (int o = 0; o < 2; ++o)
              acc[o][dh * 2 + dw] =
                  dot8(fr.x, fr.y, fr.z, fr.w, sv, W + (o * 9 + tap) * 5, acc[o][dh * 2 + dw]);
          }
        }
      }
    }
#pragma unroll
    for (int o = 0; o < 2; ++o) {
      float m = fmaxf(fmaxf(acc[o][0], acc[o][1]), fmaxf(acc[o][2], acc[o][3]));
      const int fi = o * 196 + tid;
      uint4 bm = make_basis(m);
      *(uint4*)&lds[F2DB + fi * 4] = bm;
      lds[F2SB + fi] = __float_as_uint(silu_f(m));
    }
  }
  __syncthreads();

  // ---- Stage 3: L2 conv; one wave per (o,ci), lane = 7x7 pool pos ----
  {
    const int wid = __builtin_amdgcn_readfirstlane(tid >> 6);  // = o*2+ci
    const int lane = tid & 63;
    // basis(0) (padding): halves 2..5 = {1/48, 23/48, 23/48, 1/48}
    const uint F0d1 = pack_h2f(1.0f / 48.0f, 23.0f / 48.0f);
    const uint F0d2 = pack_h2f(23.0f / 48.0f, 1.0f / 48.0f);
    if (lane < 49) {
      const int ci = wid & 1;
      const int ph = lane / 7, pw = lane % 7;
      float pa[4] = {0.0f, 0.0f, 0.0f, 0.0f};
#pragma unroll
      for (int r = 0; r < 4; ++r) {
#pragma unroll
        for (int c = 0; c < 4; ++c) {
          int row = 2 * ph + r - 1, col = 2 * pw + c - 1;
          bool ok = ((uint)row < 14u) && ((uint)col < 14u);
          int rcl = min(max(row, 0), 13), ccl = min(max(col, 0), 13);
          const int idx = ci * 196 + rcl * 14 + ccl;
          const uint4 d = *(const uint4*)&lds[F2DB + idx * 4];
          float sv = __uint_as_float(lds[F2SB + idx]);
          sv = ok ? sv : 0.0f;                  // silu(0) = 0
          uint d0 = ok ? d.x : 0u;
          uint d1 = ok ? d.y : F0d1;
          uint d2 = ok ? d.z : F0d2;
          uint d3 = ok ? d.w : 0u;
#pragma unroll
          for (int dh = 0; dh < 2; ++dh) {
            if (r - dh < 0 || r - dh > 2) continue;
#pragma unroll
            for (int dw = 0; dw < 2; ++dw) {
              if (c - dw < 0 || c - dw > 2) continue;
              const int tap = (r - dh) * 3 + (c - dw);
              pa[dh * 2 + dw] =
                  dot8(d0, d1, d2, d3, sv, W + 90 + (wid * 9 + tap) * 5, pa[dh * 2 + dw]);
            }
          }
        }
      }
      *(float4*)&P[(wid * 49 + lane) * 4] = make_float4(pa[0], pa[1], pa[2], pa[3]);
    }
  }
  __syncthreads();

  // ---- Stage 4: sum input channels, 2x2 maxpool, write (2,7,7) flat ----
  if (tid < 98) {
    const int o = tid / 49, pos = tid % 49;
    const float4 p0 = *(const float4*)&P[((o * 2 + 0) * 49 + pos) * 4];
    const float4 p1 = *(const float4*)&P[((o * 2 + 1) * 49 + pos) * 4];
    float m = fmaxf(fmaxf(p0.x + p1.x, p0.y + p1.y), fmaxf(p0.z + p1.z, p0.w + p1.w));
    out[(size_t)blockIdx.x * 98 + tid] = m;
  }
}

extern "C" void kernel_launch(void* const* d_in, const int* in_sizes, int n_in,
                              void* d_out, int out_size, void* d_ws, size_t ws_size,
                              hipStream_t stream) {
  const float* x   = (const float*)d_in[0];
  const float* bw1 = (const float*)d_in[1];
  const float* sw1 = (const float*)d_in[2];
  const float* sc1 = (const float*)d_in[3];
  const float* bw2 = (const float*)d_in[4];
  const float* sw2 = (const float*)d_in[5];
  const float* sc2 = (const float*)d_in[6];
  float* out = (float*)d_out;
  uint* W = (uint*)d_ws;  // 270 dwords
  const int B = in_sizes[0] / 784;  // 2048
  pack_w<<<1, 64, 0, stream>>>(bw1, sw1, sc1, bw2, sw2, sc2, W);
  kan_fwd<<<B, TPB, 0, stream>>>(x, W, out);
}